// Round 7
// baseline (361.902 us; speedup 1.0000x reference)
//
#include <hip/hip_runtime.h>
#include <math.h>
#include <stdint.h>

#define B_    4
#define N_    2048
#define DIM_  1024
#define H_    16
#define DH_   64
#define HID_  1024
#define RS_   3072          // qkv row stride (3*HID)
#define C2_   0.1803368801111204f   // (1/sqrt(64)) * log2(e), folded into Q columns of w_qkv

typedef unsigned short u16;
typedef unsigned int   u32;
typedef short  bf16x8 __attribute__((ext_vector_type(8)));   // 8 bf16 = 4 VGPRs (MFMA A/B frag)
typedef u16    u16x8  __attribute__((ext_vector_type(8)));   // 16B vector for bf16 data movement
typedef float  f32x4  __attribute__((ext_vector_type(4)));   // 16x16 MFMA C/D frag
typedef float  f32x16 __attribute__((ext_vector_type(16)));  // 32x32 MFMA C/D frag

__device__ inline u16 f2b(float x) {   // fp32 -> bf16, round-to-nearest-even
    u32 u = __float_as_uint(x);
    return (u16)((u + 0x7fffu + ((u >> 16) & 1u)) >> 16);
}
__device__ inline float b2f(u16 x) {
    return __uint_as_float((u32)x << 16);
}

// pack two fp32 -> two bf16 (round-half-up) in one u32: [hi16(f1) : hi16(f0)]
__device__ inline u32 pack2bf(float f0, float f1) {
    u32 u0 = __float_as_uint(f0) + 0x8000u;
    u32 u1 = __float_as_uint(f1) + 0x8000u;
    return __builtin_amdgcn_perm(u1, u0, 0x07060302u);
}

#if defined(__has_builtin)
#if __has_builtin(__builtin_amdgcn_global_load_lds)
#define USE_GLL 1
#endif
#endif

#ifdef USE_GLL
typedef const __attribute__((address_space(1))) u32* gas_ptr;
typedef __attribute__((address_space(3))) u32* las_ptr;
__device__ inline void gll16(const void* g, void* l) {
    __builtin_amdgcn_global_load_lds((gas_ptr)g, (las_ptr)l, 16, 0, 0);
}
#endif

// ---------------------------------------------------------------------------
// Elementwise fp32 -> bf16 cast (x). 8 elems/thread.
// ---------------------------------------------------------------------------
__global__ __launch_bounds__(256) void cast_bf16(const float* __restrict__ in,
                                                 u16* __restrict__ out, int n) {
    int i = (blockIdx.x * 256 + threadIdx.x) * 8;
    if (i >= n) return;
    float4 a = *(const float4*)&in[i];
    float4 b = *(const float4*)&in[i + 4];
    u16x8 p;
    p[0] = f2b(a.x); p[1] = f2b(a.y); p[2] = f2b(a.z); p[3] = f2b(a.w);
    p[4] = f2b(b.x); p[5] = f2b(b.y); p[6] = f2b(b.z); p[7] = f2b(b.w);
    *(u16x8*)&out[i] = p;
}

// ---------------------------------------------------------------------------
// W[K][Nn] fp32 -> Wt[Nn][K] bf16 (64x64 tiles). Columns < qcols scaled by C2
// (folds the attention scale*log2e into the Q projection once).
// ---------------------------------------------------------------------------
__global__ __launch_bounds__(256) void transpose_cast(const float* __restrict__ W,
                                                      u16* __restrict__ Wt,
                                                      int K, int Nn, int qcols) {
    __shared__ float t[64][65];
    const int tid = threadIdx.x;
    const int k0 = blockIdx.y * 64, n0 = blockIdx.x * 64;
    for (int idx = tid; idx < 64 * 16; idx += 256) {
        int r = idx >> 4, c4 = (idx & 15) * 4;
        float4 g = *(const float4*)&W[(size_t)(k0 + r) * Nn + n0 + c4];
        t[r][c4] = g.x; t[r][c4 + 1] = g.y; t[r][c4 + 2] = g.z; t[r][c4 + 3] = g.w;
    }
    __syncthreads();
    for (int idx = tid; idx < 64 * 8; idx += 256) {
        int n = idx >> 3, k8 = (idx & 7) * 8;
        float s = (n0 + n < qcols) ? C2_ : 1.0f;
        u16x8 p;
        #pragma unroll
        for (int u = 0; u < 8; u++) p[u] = f2b(t[k8 + u][n] * s);
        *(u16x8*)&Wt[(size_t)(n0 + n) * K + k0 + k8] = p;
    }
}

// ---------------------------------------------------------------------------
// Per-head V transpose + invl fold: vT[bh][d][j] = v[b,j,h,d] * invl[bh][j]
// ---------------------------------------------------------------------------
__global__ __launch_bounds__(256) void build_vT(const u16* __restrict__ qkvb,
                                                const float* __restrict__ invl,
                                                u16* __restrict__ vT) {
    __shared__ u16 t[64 * 72];
    __shared__ float li[64];
    const int tid = threadIdx.x;
    const int bh = blockIdx.y, b = bh >> 4, h = bh & 15;
    const int j0 = blockIdx.x * 64;
    const u16* vbase = qkvb + (size_t)b * N_ * RS_ + 2 * HID_ + h * DH_;
    for (int idx = tid; idx < 512; idx += 256) {
        int r = idx >> 3, d8 = (idx & 7) * 8;
        *(u16x8*)&t[r * 72 + d8] = *(const u16x8*)&vbase[(size_t)(j0 + r) * RS_ + d8];
    }
    if (tid < 64) li[tid] = invl[(size_t)bh * N_ + j0 + tid];
    __syncthreads();
    {
        int d = tid >> 2, j16 = (tid & 3) * 16;
        u16x8 p0, p1;
        #pragma unroll
        for (int u = 0; u < 8; u++) {
            p0[u] = f2b(b2f(t[(j16 + u) * 72 + d]) * li[j16 + u]);
            p1[u] = f2b(b2f(t[(j16 + 8 + u) * 72 + d]) * li[j16 + 8 + u]);
        }
        size_t o = ((size_t)bh * DH_ + d) * N_ + j0 + j16;
        *(u16x8*)&vT[o] = p0;
        *(u16x8*)&vT[o + 8] = p1;
    }
}

// ---------------------------------------------------------------------------
// GEMM (BT form): C[M][Nn] = A[M][K] . Bt[Nn][K]^T (+bias), bf16 in, MFMA.
// 128x128 tile, BK=32, 256 thr (4 waves in 2x2), 4x4 16x16x32 tiles/wave.
// ---------------------------------------------------------------------------
template<int BF16OUT>
__global__ __launch_bounds__(256) void gemm_bt(const u16* __restrict__ A,
                                               const u16* __restrict__ Bt,
                                               const float* __restrict__ bias,
                                               void* __restrict__ Cout,
                                               int M, int Nn, int K) {
    __shared__ u16 at[128 * 32];
    __shared__ u16 bt[128 * 32];
    const int tid = threadIdx.x;
    const int lane = tid & 63, wave = tid >> 6;
    const int wr = wave >> 1, wc = wave & 1;
    const int mlane = lane & 15, quad = lane >> 4;
    const int m0 = blockIdx.y * 128, n0 = blockIdx.x * 128;
    const int r = tid >> 2, kc = (tid & 3) * 8;

    f32x4 acc[4][4] = {};

    for (int k0 = 0; k0 < K; k0 += 32) {
        __syncthreads();
#ifdef USE_GLL
        gll16(&A[(size_t)(m0 + r) * K + k0 + kc],       &at[r * 32 + kc]);
        gll16(&A[(size_t)(m0 + r + 64) * K + k0 + kc],  &at[(r + 64) * 32 + kc]);
        gll16(&Bt[(size_t)(n0 + r) * K + k0 + kc],      &bt[r * 32 + kc]);
        gll16(&Bt[(size_t)(n0 + r + 64) * K + k0 + kc], &bt[(r + 64) * 32 + kc]);
#else
        *(u16x8*)&at[r * 32 + kc]        = *(const u16x8*)&A[(size_t)(m0 + r) * K + k0 + kc];
        *(u16x8*)&at[(r + 64) * 32 + kc] = *(const u16x8*)&A[(size_t)(m0 + r + 64) * K + k0 + kc];
        *(u16x8*)&bt[r * 32 + kc]        = *(const u16x8*)&Bt[(size_t)(n0 + r) * K + k0 + kc];
        *(u16x8*)&bt[(r + 64) * 32 + kc] = *(const u16x8*)&Bt[(size_t)(n0 + r + 64) * K + k0 + kc];
#endif
        __syncthreads();

        bf16x8 af[4], bf[4];
        #pragma unroll
        for (int rt = 0; rt < 4; rt++)
            af[rt] = *(const bf16x8*)&at[(wr * 64 + rt * 16 + mlane) * 32 + quad * 8];
        #pragma unroll
        for (int ct = 0; ct < 4; ct++)
            bf[ct] = *(const bf16x8*)&bt[(wc * 64 + ct * 16 + mlane) * 32 + quad * 8];
        #pragma unroll
        for (int rt = 0; rt < 4; rt++)
            #pragma unroll
            for (int ct = 0; ct < 4; ct++)
                acc[rt][ct] = __builtin_amdgcn_mfma_f32_16x16x32_bf16(af[rt], bf[ct], acc[rt][ct], 0, 0, 0);
    }

    const int row0 = m0 + wr * 64 + quad * 4;
    const int col0 = n0 + wc * 64 + mlane;
    #pragma unroll
    for (int rt = 0; rt < 4; rt++)
        #pragma unroll
        for (int ct = 0; ct < 4; ct++) {
            int c = col0 + ct * 16;
            float bv = (!BF16OUT && bias != nullptr) ? bias[c] : 0.f;
            #pragma unroll
            for (int reg = 0; reg < 4; reg++) {
                int rr = row0 + rt * 16 + reg;
                float v = acc[rt][ct][reg] + bv;
                if (BF16OUT) ((u16*)Cout)[(size_t)rr * Nn + c] = f2b(v);
                else         ((float*)Cout)[(size_t)rr * Nn + c] = v;
            }
        }
}

// ---------------------------------------------------------------------------
// Column softmax stats: invl[bh][j] = 1 / sum_i exp2(qs_i.k_j)  (Q pre-scaled
// by C2 in the qkv projection). S^T orientation: A=K, B=Q. K frags hoisted.
// Register-prefetch pipeline on the Q tiles (wave-private staging).
// ---------------------------------------------------------------------------
__global__ __launch_bounds__(256) void attn_stats(const u16* __restrict__ qkvb,
                                                  float* __restrict__ invl) {
    __shared__ u16 kt[64 * 72];
    __shared__ u16 qt[4][64 * 72];
    __shared__ float red[4][64];

    const int tid = threadIdx.x;
    const int lane = tid & 63, wave = tid >> 6;
    const int mlane = lane & 15, quad = lane >> 4;
    const int bh = blockIdx.y, b = bh >> 4, h = bh & 15;
    const int j0 = blockIdx.x * 64;

    const u16* qbase = qkvb + (size_t)b * N_ * RS_ + h * DH_;
    const u16* kbase = qbase + HID_;

    // K tile (pure copy; scale already folded into Q)
    for (int idx = tid; idx < 512; idx += 256) {
        int r = idx >> 3, d8 = (idx & 7) * 8;
        *(u16x8*)&kt[r * 72 + d8] = *(const u16x8*)&kbase[(size_t)(j0 + r) * RS_ + d8];
    }
    __syncthreads();

    // hoist K A-frags (loop-invariant)
    bf16x8 kf[4][2];
    #pragma unroll
    for (int t = 0; t < 4; t++)
        #pragma unroll
        for (int ks = 0; ks < 2; ks++)
            kf[t][ks] = *(const bf16x8*)&kt[(t * 16 + mlane) * 72 + ks * 32 + quad * 8];

    f32x4 acc[4] = {};   // acc[ktile][reg] : key = ktile*16 + quad*4 + reg
    u16* qw = &qt[wave][0];

    const int prr = lane >> 3, pd8 = (lane & 7) * 8;   // per-lane staging coords
    u16x8 pq[8];
    #pragma unroll
    for (int t = 0; t < 8; t++)
        pq[t] = *(const u16x8*)&qbase[(size_t)(wave * 64 + t * 8 + prr) * RS_ + pd8];

    for (int i0 = wave * 64; i0 < N_; i0 += 256) {
        #pragma unroll
        for (int t = 0; t < 8; t++)
            *(u16x8*)&qw[(t * 8 + prr) * 72 + pd8] = pq[t];
        int in = i0 + 256;
        if (in < N_) {
            #pragma unroll
            for (int t = 0; t < 8; t++)
                pq[t] = *(const u16x8*)&qbase[(size_t)(in + t * 8 + prr) * RS_ + pd8];
        }
        #pragma unroll
        for (int q4 = 0; q4 < 4; q4++) {
            bf16x8 bq0 = *(const bf16x8*)&qw[(q4 * 16 + mlane) * 72 + quad * 8];
            bf16x8 bq1 = *(const bf16x8*)&qw[(q4 * 16 + mlane) * 72 + 32 + quad * 8];
            #pragma unroll
            for (int t = 0; t < 4; t++) {
                f32x4 z = {0.f, 0.f, 0.f, 0.f};
                z = __builtin_amdgcn_mfma_f32_16x16x32_bf16(kf[t][0], bq0, z, 0, 0, 0);
                z = __builtin_amdgcn_mfma_f32_16x16x32_bf16(kf[t][1], bq1, z, 0, 0, 0);
                #pragma unroll
                for (int reg = 0; reg < 4; reg++)
                    acc[t][reg] += __builtin_amdgcn_exp2f(z[reg]);
            }
        }
    }

    #pragma unroll
    for (int t = 0; t < 4; t++)
        #pragma unroll
        for (int reg = 0; reg < 4; reg++) {
            float v = acc[t][reg];
            v += __shfl_xor(v, 1, 64);
            v += __shfl_xor(v, 2, 64);
            v += __shfl_xor(v, 4, 64);
            v += __shfl_xor(v, 8, 64);
            if (mlane == 0) red[wave][t * 16 + quad * 4 + reg] = v;
        }
    __syncthreads();
    if (tid < 64) {
        float l = red[0][tid] + red[1][tid] + red[2][tid] + red[3][tid];
        invl[(size_t)bh * N_ + j0 + tid] = 1.0f / l;
    }
}

// ---------------------------------------------------------------------------
// Apply (32x32 MFMA): S^T = K.Qs^T -> P = exp2(S^T) (registers, lane^32
// pair-swap converts C-layout to A-layout, no LDS round-trip) -> Y += P.V'.
// 128 queries/block in 2 waves (64 q/wave keeps K/V LDS reads amortized);
// grid 1024 blocks -> 4 independent barrier domains per CU.
// Single LDS buffer: Q staged over the K/V region, consumed before the loop.
// Register-prefetch pipeline on K/V tiles.
// ---------------------------------------------------------------------------
__global__ __launch_bounds__(128) void attn_apply(const u16* __restrict__ qkvb,
                                                  const u16* __restrict__ vT,
                                                  u16* __restrict__ yb) {
    __shared__ u16 S[128 * 72];   // Q (128x64) at start; then K rows 0..63, vT rows 64..127

    const int tid = threadIdx.x;                  // 0..127
    const int lane = tid & 63, wave = tid >> 6;   // wave 0..1
    const int m31 = lane & 31, half = lane >> 5;
    const int bh = blockIdx.y, b = bh >> 4, h = bh & 15;
    const int i0 = blockIdx.x * 128;

    const u16* qbase = qkvb + (size_t)b * N_ * RS_ + h * DH_;
    const u16* kbase = qbase + HID_;
    const u16* vbase = vT + (size_t)bh * DH_ * N_;

    // stage Q: 128 rows x 64 dims = 1024 chunks / 128 threads = 8 each
    for (int idx = tid; idx < 1024; idx += 128) {
        int r = idx >> 3, d8 = (idx & 7) * 8;
        *(u16x8*)&S[r * 72 + d8] = *(const u16x8*)&qbase[(size_t)(i0 + r) * RS_ + d8];
    }
    __syncthreads();

    // hoist Q B-frags: qf[qc][kstep], query = wave*64 + qc*32 + m31
    bf16x8 qf[2][4];
    #pragma unroll
    for (int qc = 0; qc < 2; qc++)
        #pragma unroll
        for (int ks = 0; ks < 4; ks++)
            qf[qc][ks] = *(const bf16x8*)&S[(wave * 64 + qc * 32 + m31) * 72 + ks * 16 + half * 8];

    // prefetch pipeline registers: 4 K-chunks + 4 V-chunks per thread
    const int pr = tid >> 3, pc8 = (tid & 7) * 8;   // pr 0..15
    u16x8 pk[4], pv[4];
    #pragma unroll
    for (int t = 0; t < 4; t++) {
        pk[t] = *(const u16x8*)&kbase[(size_t)(pr + 16 * t) * RS_ + pc8];
        pv[t] = *(const u16x8*)&vbase[(size_t)(pr + 16 * t) * N_ + pc8];
    }

    f32x16 yacc[2][2] = {};   // [qc][dtile]

    for (int j0 = 0; j0 < N_; j0 += 64) {
        __syncthreads();   // prev iteration's LDS readers done (also covers qf hoist)
        #pragma unroll
        for (int t = 0; t < 4; t++) {
            *(u16x8*)&S[(pr + 16 * t) * 72 + pc8]      = pk[t];   // K rows 0..63
            *(u16x8*)&S[(pr + 16 * t + 64) * 72 + pc8] = pv[t];   // vT rows at offset 64
        }
        __syncthreads();

        int jn = j0 + 64;
        if (jn < N_) {   // issue next tile's loads; consumed after next barrier
            #pragma unroll
            for (int t = 0; t < 4; t++) {
                pk[t] = *(const u16x8*)&kbase[(size_t)(jn + pr + 16 * t) * RS_ + pc8];
                pv[t] = *(const u16x8*)&vbase[(size_t)(pr + 16 * t) * N_ + jn + pc8];
            }
        }

        // --- S^T + P, per 32-key tile kt ---
        bf16x8 pa[2][4];   // PV A-frags [qc][ks16]
        #pragma unroll
        for (int kt = 0; kt < 2; kt++) {
            bf16x8 ka[4];
            #pragma unroll
            for (int ks = 0; ks < 4; ks++)
                ka[ks] = *(const bf16x8*)&S[(kt * 32 + m31) * 72 + ks * 16 + half * 8];

            f32x16 sc[2] = {};
            #pragma unroll
            for (int ks = 0; ks < 4; ks++)
                #pragma unroll
                for (int qc = 0; qc < 2; qc++)
                    sc[qc] = __builtin_amdgcn_mfma_f32_32x32x16_bf16(ka[ks], qf[qc][ks], sc[qc], 0, 0, 0);

            // exp2 -> pack (keys 8rb + 4*half + 2pp + {0,1}) -> lane^32 swap to A-layout
            #pragma unroll
            for (int qc = 0; qc < 2; qc++) {
                u32 U[4][2];
                #pragma unroll
                for (int rb = 0; rb < 4; rb++)
                    #pragma unroll
                    for (int pp = 0; pp < 2; pp++) {
                        float e0 = __builtin_amdgcn_exp2f(sc[qc][4 * rb + 2 * pp]);
                        float e1 = __builtin_amdgcn_exp2f(sc[qc][4 * rb + 2 * pp + 1]);
                        U[rb][pp] = pack2bf(e0, e1);
                    }
                #pragma unroll
                for (int ksl = 0; ksl < 2; ksl++) {
                    const int rb0 = 2 * ksl;
                    u32 a0 = U[rb0][0], a1 = U[rb0][1];
                    u32 b0 = U[rb0 + 1][0], b1 = U[rb0 + 1][1];
                    u32 e0 = half ? a0 : b0, e1 = half ? a1 : b1;   // expose partner's need
                    u32 g0 = (u32)__shfl_xor((int)e0, 32, 64);
                    u32 g1 = (u32)__shfl_xor((int)e1, 32, 64);
                    u32 o0 = half ? b0 : a0, o1 = half ? b1 : a1;   // own contribution
                    union { u32 u[4]; bf16x8 v; } cv;
                    cv.u[0] = half ? g0 : o0;
                    cv.u[1] = half ? g1 : o1;
                    cv.u[2] = half ? o0 : g0;
                    cv.u[3] = half ? o1 : g1;
                    pa[qc][2 * kt + ksl] = cv.v;
                }
            }
        }

        // --- Y += P @ V' (V pre-scaled by invl) ---
        #pragma unroll
        for (int ks16 = 0; ks16 < 4; ks16++) {
            bf16x8 vb0 = *(const bf16x8*)&S[(64 + m31) * 72 + ks16 * 16 + half * 8];
            bf16x8 vb1 = *(const bf16x8*)&S[(96 + m31) * 72 + ks16 * 16 + half * 8];
            #pragma unroll
            for (int qc = 0; qc < 2; qc++) {
                yacc[qc][0] = __builtin_amdgcn_mfma_f32_32x32x16_bf16(pa[qc][ks16], vb0, yacc[qc][0], 0, 0, 0);
                yacc[qc][1] = __builtin_amdgcn_mfma_f32_32x32x16_bf16(pa[qc][ks16], vb1, yacc[qc][1], 0, 0, 0);
            }
        }
    }

    // epilogue: query = i0 + wave*64 + qc*32 + (reg&3)+8*(reg>>2)+4*half, d = dt*32+m31
    #pragma unroll
    for (int qc = 0; qc < 2; qc++)
        #pragma unroll
        for (int dt = 0; dt < 2; dt++)
            #pragma unroll
            for (int reg = 0; reg < 16; reg++) {
                int q = i0 + wave * 64 + qc * 32 + (reg & 3) + 8 * (reg >> 2) + 4 * half;
                yb[((size_t)b * N_ + q) * HID_ + h * DH_ + dt * 32 + m31] = f2b(yacc[qc][dt][reg]);
            }
}

// ---------------------------------------------------------------------------
extern "C" void kernel_launch(void* const* d_in, const int* in_sizes, int n_in,
                              void* d_out, int out_size, void* d_ws, size_t ws_size,
                              hipStream_t stream) {
    (void)in_sizes; (void)n_in; (void)out_size; (void)ws_size;

    const float* x     = (const float*)d_in[0];
    const float* w_qkv = (const float*)d_in[1];
    const float* w_out = (const float*)d_in[2];
    const float* b_out = (const float*)d_in[3];

    u16* xb    = (u16*)d_ws;                          // [8192][1024]
    u16* wqkvT = xb    + (size_t)8192 * 1024;         // [3072][1024]
    u16* woutT = wqkvT + (size_t)3072 * 1024;         // [1024][1024]
    u16* qkvb  = woutT + (size_t)1024 * 1024;         // [8192][3072]
    u16* vTb   = qkvb  + (size_t)8192 * 3072;         // [64][64][2048]
    u16* yb    = vTb   + (size_t)64 * 64 * 2048;      // [8192][1024]
    float* invl = (float*)(yb + (size_t)8192 * 1024); // [64][2048]

    cast_bf16<<<4096, 256, 0, stream>>>(x, xb, 8192 * 1024);
    transpose_cast<<<dim3(3072 / 64, 1024 / 64), 256, 0, stream>>>(w_qkv, wqkvT, 1024, 3072, HID_);
    transpose_cast<<<dim3(1024 / 64, 1024 / 64), 256, 0, stream>>>(w_out, woutT, 1024, 1024, 0);

    gemm_bt<1><<<dim3(3072 / 128, 8192 / 128), 256, 0, stream>>>(
        xb, wqkvT, nullptr, qkvb, 8192, 3072, 1024);

    attn_stats<<<dim3(N_ / 64, 64), 256, 0, stream>>>(qkvb, invl);
    build_vT<<<dim3(N_ / 64, 64), 256, 0, stream>>>(qkvb, invl, vTb);
    attn_apply<<<dim3(N_ / 128, 64), 128, 0, stream>>>(qkvb, vTb, yb);

    gemm_bt<0><<<dim3(1024 / 128, 8192 / 128), 256, 0, stream>>>(
        yb, woutT, b_out, d_out, 8192, 1024, 1024);
}

// Round 8
// 356.541 us; speedup vs baseline: 1.0150x; 1.0150x over previous
//
#include <hip/hip_runtime.h>
#include <math.h>
#include <stdint.h>

#define B_    4
#define N_    2048
#define DIM_  1024
#define H_    16
#define DH_   64
#define HID_  1024
#define RS_   3072          // qkv row stride (3*HID)
#define C2_   0.1803368801111204f   // (1/sqrt(64)) * log2(e), folded into Q columns of w_qkv

typedef unsigned short u16;
typedef unsigned int   u32;
typedef short  bf16x8 __attribute__((ext_vector_type(8)));   // 8 bf16 = 4 VGPRs (MFMA A/B frag)
typedef u16    u16x8  __attribute__((ext_vector_type(8)));   // 16B vector for bf16 data movement
typedef float  f32x4  __attribute__((ext_vector_type(4)));   // 16x16 MFMA C/D frag
typedef float  f32x16 __attribute__((ext_vector_type(16)));  // 32x32 MFMA C/D frag

__device__ inline u16 f2b(float x) {   // fp32 -> bf16, round-to-nearest-even
    u32 u = __float_as_uint(x);
    return (u16)((u + 0x7fffu + ((u >> 16) & 1u)) >> 16);
}
__device__ inline float b2f(u16 x) {
    return __uint_as_float((u32)x << 16);
}

// pack two fp32 -> two bf16 (round-half-up) in one u32: [hi16(f1) : hi16(f0)]
__device__ inline u32 pack2bf(float f0, float f1) {
    u32 u0 = __float_as_uint(f0) + 0x8000u;
    u32 u1 = __float_as_uint(f1) + 0x8000u;
    return __builtin_amdgcn_perm(u1, u0, 0x07060302u);
}

#if defined(__has_builtin)
#if __has_builtin(__builtin_amdgcn_global_load_lds)
#define USE_GLL 1
#endif
#endif

#ifdef USE_GLL
typedef const __attribute__((address_space(1))) u32* gas_ptr;
typedef __attribute__((address_space(3))) u32* las_ptr;
__device__ inline void gll16(const void* g, void* l) {
    __builtin_amdgcn_global_load_lds((gas_ptr)g, (las_ptr)l, 16, 0, 0);
}
#endif

// ---------------------------------------------------------------------------
// Elementwise fp32 -> bf16 cast (x). 8 elems/thread.
// ---------------------------------------------------------------------------
__global__ __launch_bounds__(256) void cast_bf16(const float* __restrict__ in,
                                                 u16* __restrict__ out, int n) {
    int i = (blockIdx.x * 256 + threadIdx.x) * 8;
    if (i >= n) return;
    float4 a = *(const float4*)&in[i];
    float4 b = *(const float4*)&in[i + 4];
    u16x8 p;
    p[0] = f2b(a.x); p[1] = f2b(a.y); p[2] = f2b(a.z); p[3] = f2b(a.w);
    p[4] = f2b(b.x); p[5] = f2b(b.y); p[6] = f2b(b.z); p[7] = f2b(b.w);
    *(u16x8*)&out[i] = p;
}

// ---------------------------------------------------------------------------
// W[K][Nn] fp32 -> Wt[Nn][K] bf16 (64x64 tiles). Columns < qcols scaled by C2
// (folds the attention scale*log2e into the Q projection once).
// ---------------------------------------------------------------------------
__global__ __launch_bounds__(256) void transpose_cast(const float* __restrict__ W,
                                                      u16* __restrict__ Wt,
                                                      int K, int Nn, int qcols) {
    __shared__ float t[64][65];
    const int tid = threadIdx.x;
    const int k0 = blockIdx.y * 64, n0 = blockIdx.x * 64;
    for (int idx = tid; idx < 64 * 16; idx += 256) {
        int r = idx >> 4, c4 = (idx & 15) * 4;
        float4 g = *(const float4*)&W[(size_t)(k0 + r) * Nn + n0 + c4];
        t[r][c4] = g.x; t[r][c4 + 1] = g.y; t[r][c4 + 2] = g.z; t[r][c4 + 3] = g.w;
    }
    __syncthreads();
    for (int idx = tid; idx < 64 * 8; idx += 256) {
        int n = idx >> 3, k8 = (idx & 7) * 8;
        float s = (n0 + n < qcols) ? C2_ : 1.0f;
        u16x8 p;
        #pragma unroll
        for (int u = 0; u < 8; u++) p[u] = f2b(t[k8 + u][n] * s);
        *(u16x8*)&Wt[(size_t)(n0 + n) * K + k0 + k8] = p;
    }
}

// ---------------------------------------------------------------------------
// Per-head V transpose + invl fold: vT[bh][d][j] = v[b,j,h,d] * invl[bh][j]
// ---------------------------------------------------------------------------
__global__ __launch_bounds__(256) void build_vT(const u16* __restrict__ qkvb,
                                                const float* __restrict__ invl,
                                                u16* __restrict__ vT) {
    __shared__ u16 t[64 * 72];
    __shared__ float li[64];
    const int tid = threadIdx.x;
    const int bh = blockIdx.y, b = bh >> 4, h = bh & 15;
    const int j0 = blockIdx.x * 64;
    const u16* vbase = qkvb + (size_t)b * N_ * RS_ + 2 * HID_ + h * DH_;
    for (int idx = tid; idx < 512; idx += 256) {
        int r = idx >> 3, d8 = (idx & 7) * 8;
        *(u16x8*)&t[r * 72 + d8] = *(const u16x8*)&vbase[(size_t)(j0 + r) * RS_ + d8];
    }
    if (tid < 64) li[tid] = invl[(size_t)bh * N_ + j0 + tid];
    __syncthreads();
    {
        int d = tid >> 2, j16 = (tid & 3) * 16;
        u16x8 p0, p1;
        #pragma unroll
        for (int u = 0; u < 8; u++) {
            p0[u] = f2b(b2f(t[(j16 + u) * 72 + d]) * li[j16 + u]);
            p1[u] = f2b(b2f(t[(j16 + 8 + u) * 72 + d]) * li[j16 + 8 + u]);
        }
        size_t o = ((size_t)bh * DH_ + d) * N_ + j0 + j16;
        *(u16x8*)&vT[o] = p0;
        *(u16x8*)&vT[o + 8] = p1;
    }
}

// ---------------------------------------------------------------------------
// GEMM (BT form): C[M][Nn] = A[M][K] . Bt[Nn][K]^T (+bias), bf16 in, MFMA.
// 128x128 tile, BK=32, 256 thr (4 waves in 2x2), 4x4 16x16x32 tiles/wave.
// 1-D grid, XCD-swizzled: mt = (id&7)*8 + ((id>>3)&7), nt = id>>6 — all
// blocks sharing an A row-band land on one XCD (A fetched once per chip).
// ---------------------------------------------------------------------------
template<int BF16OUT>
__global__ __launch_bounds__(256) void gemm_bt(const u16* __restrict__ A,
                                               const u16* __restrict__ Bt,
                                               const float* __restrict__ bias,
                                               void* __restrict__ Cout,
                                               int M, int Nn, int K) {
    __shared__ u16 at[128 * 32];
    __shared__ u16 bt[128 * 32];
    const int tid = threadIdx.x;
    const int lane = tid & 63, wave = tid >> 6;
    const int wr = wave >> 1, wc = wave & 1;
    const int mlane = lane & 15, quad = lane >> 4;
    const int id = blockIdx.x;
    const int mt = (id & 7) * 8 + ((id >> 3) & 7);
    const int nt = id >> 6;
    const int m0 = mt * 128, n0 = nt * 128;
    const int r = tid >> 2, kc = (tid & 3) * 8;

    f32x4 acc[4][4] = {};

    for (int k0 = 0; k0 < K; k0 += 32) {
        __syncthreads();
#ifdef USE_GLL
        gll16(&A[(size_t)(m0 + r) * K + k0 + kc],       &at[r * 32 + kc]);
        gll16(&A[(size_t)(m0 + r + 64) * K + k0 + kc],  &at[(r + 64) * 32 + kc]);
        gll16(&Bt[(size_t)(n0 + r) * K + k0 + kc],      &bt[r * 32 + kc]);
        gll16(&Bt[(size_t)(n0 + r + 64) * K + k0 + kc], &bt[(r + 64) * 32 + kc]);
#else
        *(u16x8*)&at[r * 32 + kc]        = *(const u16x8*)&A[(size_t)(m0 + r) * K + k0 + kc];
        *(u16x8*)&at[(r + 64) * 32 + kc] = *(const u16x8*)&A[(size_t)(m0 + r + 64) * K + k0 + kc];
        *(u16x8*)&bt[r * 32 + kc]        = *(const u16x8*)&Bt[(size_t)(n0 + r) * K + k0 + kc];
        *(u16x8*)&bt[(r + 64) * 32 + kc] = *(const u16x8*)&Bt[(size_t)(n0 + r + 64) * K + k0 + kc];
#endif
        __syncthreads();

        bf16x8 af[4], bf[4];
        #pragma unroll
        for (int rt = 0; rt < 4; rt++)
            af[rt] = *(const bf16x8*)&at[(wr * 64 + rt * 16 + mlane) * 32 + quad * 8];
        #pragma unroll
        for (int ct = 0; ct < 4; ct++)
            bf[ct] = *(const bf16x8*)&bt[(wc * 64 + ct * 16 + mlane) * 32 + quad * 8];
        #pragma unroll
        for (int rt = 0; rt < 4; rt++)
            #pragma unroll
            for (int ct = 0; ct < 4; ct++)
                acc[rt][ct] = __builtin_amdgcn_mfma_f32_16x16x32_bf16(af[rt], bf[ct], acc[rt][ct], 0, 0, 0);
    }

    const int row0 = m0 + wr * 64 + quad * 4;
    const int col0 = n0 + wc * 64 + mlane;
    #pragma unroll
    for (int rt = 0; rt < 4; rt++)
        #pragma unroll
        for (int ct = 0; ct < 4; ct++) {
            int c = col0 + ct * 16;
            float bv = (!BF16OUT && bias != nullptr) ? bias[c] : 0.f;
            #pragma unroll
            for (int reg = 0; reg < 4; reg++) {
                int rr = row0 + rt * 16 + reg;
                float v = acc[rt][ct][reg] + bv;
                if (BF16OUT) ((u16*)Cout)[(size_t)rr * Nn + c] = f2b(v);
                else         ((float*)Cout)[(size_t)rr * Nn + c] = v;
            }
        }
}

// ---------------------------------------------------------------------------
// Column softmax stats: invl[bh][j] = 1 / sum_i exp2(qs_i.k_j)  (Q pre-scaled
// by C2 in the qkv projection). S^T orientation: A=K, B=Q. K frags hoisted.
// 1-D grid XCD-swizzled: all 32 j-tile blocks of one head share an XCD
// (the head's Q, read fully by each block, is fetched into one L2 only).
// ---------------------------------------------------------------------------
__global__ __launch_bounds__(256) void attn_stats(const u16* __restrict__ qkvb,
                                                  float* __restrict__ invl) {
    __shared__ u16 kt[64 * 72];
    __shared__ u16 qt[4][64 * 72];
    __shared__ float red[4][64];

    const int tid = threadIdx.x;
    const int lane = tid & 63, wave = tid >> 6;
    const int mlane = lane & 15, quad = lane >> 4;
    const int id = blockIdx.x;
    const int bh = (id & 7) * 8 + ((id >> 3) & 7);
    const int b = bh >> 4, h = bh & 15;
    const int j0 = (id >> 6) * 64;

    const u16* qbase = qkvb + (size_t)b * N_ * RS_ + h * DH_;
    const u16* kbase = qbase + HID_;

    // K tile (pure copy; scale already folded into Q)
    for (int idx = tid; idx < 512; idx += 256) {
        int r = idx >> 3, d8 = (idx & 7) * 8;
        *(u16x8*)&kt[r * 72 + d8] = *(const u16x8*)&kbase[(size_t)(j0 + r) * RS_ + d8];
    }
    __syncthreads();

    // hoist K A-frags (loop-invariant)
    bf16x8 kf[4][2];
    #pragma unroll
    for (int t = 0; t < 4; t++)
        #pragma unroll
        for (int ks = 0; ks < 2; ks++)
            kf[t][ks] = *(const bf16x8*)&kt[(t * 16 + mlane) * 72 + ks * 32 + quad * 8];

    f32x4 acc[4] = {};   // acc[ktile][reg] : key = ktile*16 + quad*4 + reg
    u16* qw = &qt[wave][0];

    const int prr = lane >> 3, pd8 = (lane & 7) * 8;   // per-lane staging coords
    u16x8 pq[8];
    #pragma unroll
    for (int t = 0; t < 8; t++)
        pq[t] = *(const u16x8*)&qbase[(size_t)(wave * 64 + t * 8 + prr) * RS_ + pd8];

    for (int i0 = wave * 64; i0 < N_; i0 += 256) {
        #pragma unroll
        for (int t = 0; t < 8; t++)
            *(u16x8*)&qw[(t * 8 + prr) * 72 + pd8] = pq[t];
        int in = i0 + 256;
        if (in < N_) {
            #pragma unroll
            for (int t = 0; t < 8; t++)
                pq[t] = *(const u16x8*)&qbase[(size_t)(in + t * 8 + prr) * RS_ + pd8];
        }
        #pragma unroll
        for (int q4 = 0; q4 < 4; q4++) {
            bf16x8 bq0 = *(const bf16x8*)&qw[(q4 * 16 + mlane) * 72 + quad * 8];
            bf16x8 bq1 = *(const bf16x8*)&qw[(q4 * 16 + mlane) * 72 + 32 + quad * 8];
            #pragma unroll
            for (int t = 0; t < 4; t++) {
                f32x4 z = {0.f, 0.f, 0.f, 0.f};
                z = __builtin_amdgcn_mfma_f32_16x16x32_bf16(kf[t][0], bq0, z, 0, 0, 0);
                z = __builtin_amdgcn_mfma_f32_16x16x32_bf16(kf[t][1], bq1, z, 0, 0, 0);
                #pragma unroll
                for (int reg = 0; reg < 4; reg++)
                    acc[t][reg] += __builtin_amdgcn_exp2f(z[reg]);
            }
        }
    }

    #pragma unroll
    for (int t = 0; t < 4; t++)
        #pragma unroll
        for (int reg = 0; reg < 4; reg++) {
            float v = acc[t][reg];
            v += __shfl_xor(v, 1, 64);
            v += __shfl_xor(v, 2, 64);
            v += __shfl_xor(v, 4, 64);
            v += __shfl_xor(v, 8, 64);
            if (mlane == 0) red[wave][t * 16 + quad * 4 + reg] = v;
        }
    __syncthreads();
    if (tid < 64) {
        float l = red[0][tid] + red[1][tid] + red[2][tid] + red[3][tid];
        invl[(size_t)bh * N_ + j0 + tid] = 1.0f / l;
    }
}

// ---------------------------------------------------------------------------
// Apply (32x32 MFMA): S^T = K.Qs^T -> P = exp2(S^T) (registers, lane^32
// pair-swap converts C-layout to A-layout) -> Y += P.V'.
// 128 queries/block in 2 waves. 1-D grid XCD-swizzled: all 16 query-tile
// blocks of one head share an XCD, so the head's K/vT (read fully by every
// block) is fetched into exactly one per-XCD L2 instead of all eight.
// Register-prefetch pipeline on K/V tiles; Q LDS aliased over K/V region.
// ---------------------------------------------------------------------------
__global__ __launch_bounds__(128) void attn_apply(const u16* __restrict__ qkvb,
                                                  const u16* __restrict__ vT,
                                                  u16* __restrict__ yb) {
    __shared__ u16 S[128 * 72];   // Q (128x64) at start; then K rows 0..63, vT rows 64..127

    const int tid = threadIdx.x;                  // 0..127
    const int lane = tid & 63, wave = tid >> 6;   // wave 0..1
    const int m31 = lane & 31, half = lane >> 5;
    const int id = blockIdx.x;
    const int bh = (id & 7) * 8 + ((id >> 3) & 7);
    const int b = bh >> 4, h = bh & 15;
    const int i0 = (id >> 6) * 128;

    const u16* qbase = qkvb + (size_t)b * N_ * RS_ + h * DH_;
    const u16* kbase = qbase + HID_;
    const u16* vbase = vT + (size_t)bh * DH_ * N_;

    // stage Q: 128 rows x 64 dims = 1024 chunks / 128 threads = 8 each
    for (int idx = tid; idx < 1024; idx += 128) {
        int r = idx >> 3, d8 = (idx & 7) * 8;
        *(u16x8*)&S[r * 72 + d8] = *(const u16x8*)&qbase[(size_t)(i0 + r) * RS_ + d8];
    }
    __syncthreads();

    // hoist Q B-frags: qf[qc][kstep], query = wave*64 + qc*32 + m31
    bf16x8 qf[2][4];
    #pragma unroll
    for (int qc = 0; qc < 2; qc++)
        #pragma unroll
        for (int ks = 0; ks < 4; ks++)
            qf[qc][ks] = *(const bf16x8*)&S[(wave * 64 + qc * 32 + m31) * 72 + ks * 16 + half * 8];

    // prefetch pipeline registers: 4 K-chunks + 4 V-chunks per thread
    const int pr = tid >> 3, pc8 = (tid & 7) * 8;   // pr 0..15
    u16x8 pk[4], pv[4];
    #pragma unroll
    for (int t = 0; t < 4; t++) {
        pk[t] = *(const u16x8*)&kbase[(size_t)(pr + 16 * t) * RS_ + pc8];
        pv[t] = *(const u16x8*)&vbase[(size_t)(pr + 16 * t) * N_ + pc8];
    }

    f32x16 yacc[2][2] = {};   // [qc][dtile]

    for (int j0 = 0; j0 < N_; j0 += 64) {
        __syncthreads();   // prev iteration's LDS readers done (also covers qf hoist)
        #pragma unroll
        for (int t = 0; t < 4; t++) {
            *(u16x8*)&S[(pr + 16 * t) * 72 + pc8]      = pk[t];   // K rows 0..63
            *(u16x8*)&S[(pr + 16 * t + 64) * 72 + pc8] = pv[t];   // vT rows at offset 64
        }
        __syncthreads();

        int jn = j0 + 64;
        if (jn < N_) {   // issue next tile's loads; consumed after next barrier
            #pragma unroll
            for (int t = 0; t < 4; t++) {
                pk[t] = *(const u16x8*)&kbase[(size_t)(jn + pr + 16 * t) * RS_ + pc8];
                pv[t] = *(const u16x8*)&vbase[(size_t)(pr + 16 * t) * N_ + jn + pc8];
            }
        }

        // --- S^T + P, per 32-key tile kt ---
        bf16x8 pa[2][4];   // PV A-frags [qc][ks16]
        #pragma unroll
        for (int kt = 0; kt < 2; kt++) {
            bf16x8 ka[4];
            #pragma unroll
            for (int ks = 0; ks < 4; ks++)
                ka[ks] = *(const bf16x8*)&S[(kt * 32 + m31) * 72 + ks * 16 + half * 8];

            f32x16 sc[2] = {};
            #pragma unroll
            for (int ks = 0; ks < 4; ks++)
                #pragma unroll
                for (int qc = 0; qc < 2; qc++)
                    sc[qc] = __builtin_amdgcn_mfma_f32_32x32x16_bf16(ka[ks], qf[qc][ks], sc[qc], 0, 0, 0);

            // exp2 -> pack (keys 8rb + 4*half + 2pp + {0,1}) -> lane^32 swap to A-layout
            #pragma unroll
            for (int qc = 0; qc < 2; qc++) {
                u32 U[4][2];
                #pragma unroll
                for (int rb = 0; rb < 4; rb++)
                    #pragma unroll
                    for (int pp = 0; pp < 2; pp++) {
                        float e0 = __builtin_amdgcn_exp2f(sc[qc][4 * rb + 2 * pp]);
                        float e1 = __builtin_amdgcn_exp2f(sc[qc][4 * rb + 2 * pp + 1]);
                        U[rb][pp] = pack2bf(e0, e1);
                    }
                #pragma unroll
                for (int ksl = 0; ksl < 2; ksl++) {
                    const int rb0 = 2 * ksl;
                    u32 a0 = U[rb0][0], a1 = U[rb0][1];
                    u32 b0 = U[rb0 + 1][0], b1 = U[rb0 + 1][1];
                    u32 e0 = half ? a0 : b0, e1 = half ? a1 : b1;   // expose partner's need
                    u32 g0 = (u32)__shfl_xor((int)e0, 32, 64);
                    u32 g1 = (u32)__shfl_xor((int)e1, 32, 64);
                    u32 o0 = half ? b0 : a0, o1 = half ? b1 : a1;   // own contribution
                    union { u32 u[4]; bf16x8 v; } cv;
                    cv.u[0] = half ? g0 : o0;
                    cv.u[1] = half ? g1 : o1;
                    cv.u[2] = half ? o0 : g0;
                    cv.u[3] = half ? o1 : g1;
                    pa[qc][2 * kt + ksl] = cv.v;
                }
            }
        }

        // --- Y += P @ V' (V pre-scaled by invl) ---
        #pragma unroll
        for (int ks16 = 0; ks16 < 4; ks16++) {
            bf16x8 vb0 = *(const bf16x8*)&S[(64 + m31) * 72 + ks16 * 16 + half * 8];
            bf16x8 vb1 = *(const bf16x8*)&S[(96 + m31) * 72 + ks16 * 16 + half * 8];
            #pragma unroll
            for (int qc = 0; qc < 2; qc++) {
                yacc[qc][0] = __builtin_amdgcn_mfma_f32_32x32x16_bf16(pa[qc][ks16], vb0, yacc[qc][0], 0, 0, 0);
                yacc[qc][1] = __builtin_amdgcn_mfma_f32_32x32x16_bf16(pa[qc][ks16], vb1, yacc[qc][1], 0, 0, 0);
            }
        }
    }

    // epilogue: query = i0 + wave*64 + qc*32 + (reg&3)+8*(reg>>2)+4*half, d = dt*32+m31
    #pragma unroll
    for (int qc = 0; qc < 2; qc++)
        #pragma unroll
        for (int dt = 0; dt < 2; dt++)
            #pragma unroll
            for (int reg = 0; reg < 16; reg++) {
                int q = i0 + wave * 64 + qc * 32 + (reg & 3) + 8 * (reg >> 2) + 4 * half;
                yb[((size_t)b * N_ + q) * HID_ + h * DH_ + dt * 32 + m31] = f2b(yacc[qc][dt][reg]);
            }
}

// ---------------------------------------------------------------------------
extern "C" void kernel_launch(void* const* d_in, const int* in_sizes, int n_in,
                              void* d_out, int out_size, void* d_ws, size_t ws_size,
                              hipStream_t stream) {
    (void)in_sizes; (void)n_in; (void)out_size; (void)ws_size;

    const float* x     = (const float*)d_in[0];
    const float* w_qkv = (const float*)d_in[1];
    const float* w_out = (const float*)d_in[2];
    const float* b_out = (const float*)d_in[3];

    u16* xb    = (u16*)d_ws;                          // [8192][1024]
    u16* wqkvT = xb    + (size_t)8192 * 1024;         // [3072][1024]
    u16* woutT = wqkvT + (size_t)3072 * 1024;         // [1024][1024]
    u16* qkvb  = woutT + (size_t)1024 * 1024;         // [8192][3072]
    u16* vTb   = qkvb  + (size_t)8192 * 3072;         // [64][64][2048]
    u16* yb    = vTb   + (size_t)64 * 64 * 2048;      // [8192][1024]
    float* invl = (float*)(yb + (size_t)8192 * 1024); // [64][2048]

    cast_bf16<<<4096, 256, 0, stream>>>(x, xb, 8192 * 1024);
    transpose_cast<<<dim3(3072 / 64, 1024 / 64), 256, 0, stream>>>(w_qkv, wqkvT, 1024, 3072, HID_);
    transpose_cast<<<dim3(1024 / 64, 1024 / 64), 256, 0, stream>>>(w_out, woutT, 1024, 1024, 0);

    // grid = 64 m-tiles * 24 n-tiles, XCD-swizzled inside the kernel
    gemm_bt<1><<<64 * 24, 256, 0, stream>>>(
        xb, wqkvT, nullptr, qkvb, 8192, 3072, 1024);

    // grid = 32 j-tiles * 64 heads, XCD-swizzled
    attn_stats<<<32 * 64, 256, 0, stream>>>(qkvb, invl);
    build_vT<<<dim3(N_ / 64, 64), 256, 0, stream>>>(qkvb, invl, vTb);
    // grid = 16 q-tiles * 64 heads, XCD-swizzled
    attn_apply<<<16 * 64, 128, 0, stream>>>(qkvb, vTb, yb);

    // grid = 64 m-tiles * 8 n-tiles, XCD-swizzled
    gemm_bt<0><<<64 * 8, 256, 0, stream>>>(
        yb, woutT, b_out, d_out, 8192, 1024, 1024);
}

// Round 9
// 350.399 us; speedup vs baseline: 1.0328x; 1.0175x over previous
//
#include <hip/hip_runtime.h>
#include <math.h>
#include <stdint.h>

#define B_    4
#define N_    2048
#define DIM_  1024
#define H_    16
#define DH_   64
#define HID_  1024
#define RS_   3072          // qkv row stride (3*HID)
#define C2_   0.1803368801111204f   // (1/sqrt(64)) * log2(e), folded into Q columns of w_qkv

typedef unsigned short u16;
typedef unsigned int   u32;
typedef short  bf16x8 __attribute__((ext_vector_type(8)));   // 8 bf16 = 4 VGPRs (MFMA A/B frag)
typedef u16    u16x8  __attribute__((ext_vector_type(8)));   // 16B vector for bf16 data movement
typedef float  f32x4  __attribute__((ext_vector_type(4)));   // 16x16 MFMA C/D frag
typedef float  f32x16 __attribute__((ext_vector_type(16)));  // 32x32 MFMA C/D frag

__device__ inline u16 f2b(float x) {   // fp32 -> bf16, round-to-nearest-even
    u32 u = __float_as_uint(x);
    return (u16)((u + 0x7fffu + ((u >> 16) & 1u)) >> 16);
}
__device__ inline float b2f(u16 x) {
    return __uint_as_float((u32)x << 16);
}

// pack two fp32 -> two bf16 (round-half-up) in one u32: [hi16(f1) : hi16(f0)]
__device__ inline u32 pack2bf(float f0, float f1) {
    u32 u0 = __float_as_uint(f0) + 0x8000u;
    u32 u1 = __float_as_uint(f1) + 0x8000u;
    return __builtin_amdgcn_perm(u1, u0, 0x07060302u);
}

#if defined(__has_builtin)
#if __has_builtin(__builtin_amdgcn_global_load_lds)
#define USE_GLL 1
#endif
#endif

#ifdef USE_GLL
typedef const __attribute__((address_space(1))) u32* gas_ptr;
typedef __attribute__((address_space(3))) u32* las_ptr;
__device__ inline void gll16(const void* g, void* l) {
    __builtin_amdgcn_global_load_lds((gas_ptr)g, (las_ptr)l, 16, 0, 0);
}
#endif

// ---------------------------------------------------------------------------
// Elementwise fp32 -> bf16 cast (x). 8 elems/thread.
// ---------------------------------------------------------------------------
__global__ __launch_bounds__(256) void cast_bf16(const float* __restrict__ in,
                                                 u16* __restrict__ out, int n) {
    int i = (blockIdx.x * 256 + threadIdx.x) * 8;
    if (i >= n) return;
    float4 a = *(const float4*)&in[i];
    float4 b = *(const float4*)&in[i + 4];
    u16x8 p;
    p[0] = f2b(a.x); p[1] = f2b(a.y); p[2] = f2b(a.z); p[3] = f2b(a.w);
    p[4] = f2b(b.x); p[5] = f2b(b.y); p[6] = f2b(b.z); p[7] = f2b(b.w);
    *(u16x8*)&out[i] = p;
}

// ---------------------------------------------------------------------------
// W[K][Nn] fp32 -> Wt[Nn][K] bf16 (64x64 tiles). Columns < qcols scaled by C2
// (folds the attention scale*log2e into the Q projection once).
// ---------------------------------------------------------------------------
__global__ __launch_bounds__(256) void transpose_cast(const float* __restrict__ W,
                                                      u16* __restrict__ Wt,
                                                      int K, int Nn, int qcols) {
    __shared__ float t[64][65];
    const int tid = threadIdx.x;
    const int k0 = blockIdx.y * 64, n0 = blockIdx.x * 64;
    for (int idx = tid; idx < 64 * 16; idx += 256) {
        int r = idx >> 4, c4 = (idx & 15) * 4;
        float4 g = *(const float4*)&W[(size_t)(k0 + r) * Nn + n0 + c4];
        t[r][c4] = g.x; t[r][c4 + 1] = g.y; t[r][c4 + 2] = g.z; t[r][c4 + 3] = g.w;
    }
    __syncthreads();
    for (int idx = tid; idx < 64 * 8; idx += 256) {
        int n = idx >> 3, k8 = (idx & 7) * 8;
        float s = (n0 + n < qcols) ? C2_ : 1.0f;
        u16x8 p;
        #pragma unroll
        for (int u = 0; u < 8; u++) p[u] = f2b(t[k8 + u][n] * s);
        *(u16x8*)&Wt[(size_t)(n0 + n) * K + k0 + k8] = p;
    }
}

// ---------------------------------------------------------------------------
// GEMM (BT form): C[M][Nn] = A[M][K] . Bt[Nn][K]^T (+bias), bf16 in, MFMA.
// 128x128 tile, BK=32, 256 thr (4 waves in 2x2), 4x4 16x16x32 tiles/wave.
// 1-D grid, XCD-swizzled: mt = (id&7)*8 + ((id>>3)&7), nt = id>>6 — all
// blocks sharing an A row-band land on one XCD (A fetched once per chip).
// [R8: this swizzle was worth ~-15us on the two gemms — keep.]
// ---------------------------------------------------------------------------
template<int BF16OUT>
__global__ __launch_bounds__(256) void gemm_bt(const u16* __restrict__ A,
                                               const u16* __restrict__ Bt,
                                               const float* __restrict__ bias,
                                               void* __restrict__ Cout,
                                               int M, int Nn, int K) {
    __shared__ u16 at[128 * 32];
    __shared__ u16 bt[128 * 32];
    const int tid = threadIdx.x;
    const int lane = tid & 63, wave = tid >> 6;
    const int wr = wave >> 1, wc = wave & 1;
    const int mlane = lane & 15, quad = lane >> 4;
    const int id = blockIdx.x;
    const int mt = (id & 7) * 8 + ((id >> 3) & 7);
    const int nt = id >> 6;
    const int m0 = mt * 128, n0 = nt * 128;
    const int r = tid >> 2, kc = (tid & 3) * 8;

    f32x4 acc[4][4] = {};

    for (int k0 = 0; k0 < K; k0 += 32) {
        __syncthreads();
#ifdef USE_GLL
        gll16(&A[(size_t)(m0 + r) * K + k0 + kc],       &at[r * 32 + kc]);
        gll16(&A[(size_t)(m0 + r + 64) * K + k0 + kc],  &at[(r + 64) * 32 + kc]);
        gll16(&Bt[(size_t)(n0 + r) * K + k0 + kc],      &bt[r * 32 + kc]);
        gll16(&Bt[(size_t)(n0 + r + 64) * K + k0 + kc], &bt[(r + 64) * 32 + kc]);
#else
        *(u16x8*)&at[r * 32 + kc]        = *(const u16x8*)&A[(size_t)(m0 + r) * K + k0 + kc];
        *(u16x8*)&at[(r + 64) * 32 + kc] = *(const u16x8*)&A[(size_t)(m0 + r + 64) * K + k0 + kc];
        *(u16x8*)&bt[r * 32 + kc]        = *(const u16x8*)&Bt[(size_t)(n0 + r) * K + k0 + kc];
        *(u16x8*)&bt[(r + 64) * 32 + kc] = *(const u16x8*)&Bt[(size_t)(n0 + r + 64) * K + k0 + kc];
#endif
        __syncthreads();

        bf16x8 af[4], bf[4];
        #pragma unroll
        for (int rt = 0; rt < 4; rt++)
            af[rt] = *(const bf16x8*)&at[(wr * 64 + rt * 16 + mlane) * 32 + quad * 8];
        #pragma unroll
        for (int ct = 0; ct < 4; ct++)
            bf[ct] = *(const bf16x8*)&bt[(wc * 64 + ct * 16 + mlane) * 32 + quad * 8];
        #pragma unroll
        for (int rt = 0; rt < 4; rt++)
            #pragma unroll
            for (int ct = 0; ct < 4; ct++)
                acc[rt][ct] = __builtin_amdgcn_mfma_f32_16x16x32_bf16(af[rt], bf[ct], acc[rt][ct], 0, 0, 0);
    }

    const int row0 = m0 + wr * 64 + quad * 4;
    const int col0 = n0 + wc * 64 + mlane;
    #pragma unroll
    for (int rt = 0; rt < 4; rt++)
        #pragma unroll
        for (int ct = 0; ct < 4; ct++) {
            int c = col0 + ct * 16;
            float bv = (!BF16OUT && bias != nullptr) ? bias[c] : 0.f;
            #pragma unroll
            for (int reg = 0; reg < 4; reg++) {
                int rr = row0 + rt * 16 + reg;
                float v = acc[rt][ct][reg] + bv;
                if (BF16OUT) ((u16*)Cout)[(size_t)rr * Nn + c] = f2b(v);
                else         ((float*)Cout)[(size_t)rr * Nn + c] = v;
            }
        }
}

// ---------------------------------------------------------------------------
// FUSED stats + V-transpose. Per (head, 64-key tile) block:
//  1) invl_j = 1 / sum_i exp2(qs_i.k_j) over all queries (MFMA S^T sweep);
//  2) vT[bh][d][j] = v[b,j,h,d] * invl_j (scale+transpose via LDS, reusing
//     the K buffer — K frags live in registers by then).
// Kills the separate build_vT pass + the invl global round-trip.
// 1-D grid XCD-swizzled: all 32 j-tile blocks of one head share an XCD.
// ---------------------------------------------------------------------------
__global__ __launch_bounds__(256) void attn_stats_vt(const u16* __restrict__ qkvb,
                                                     u16* __restrict__ vT) {
    __shared__ u16 kt[64 * 72];       // K tile, then reused as the V tile
    __shared__ u16 qt[4][64 * 72];
    __shared__ float red[4][64];
    __shared__ float li[64];

    const int tid = threadIdx.x;
    const int lane = tid & 63, wave = tid >> 6;
    const int mlane = lane & 15, quad = lane >> 4;
    const int id = blockIdx.x;
    const int bh = (id & 7) * 8 + ((id >> 3) & 7);
    const int b = bh >> 4, h = bh & 15;
    const int j0 = (id >> 6) * 64;

    const u16* qbase = qkvb + (size_t)b * N_ * RS_ + h * DH_;
    const u16* kbase = qbase + HID_;
    const u16* vbase = qbase + 2 * HID_;

    // K tile (pure copy; scale already folded into Q)
    for (int idx = tid; idx < 512; idx += 256) {
        int r = idx >> 3, d8 = (idx & 7) * 8;
        *(u16x8*)&kt[r * 72 + d8] = *(const u16x8*)&kbase[(size_t)(j0 + r) * RS_ + d8];
    }
    __syncthreads();

    // hoist K A-frags (loop-invariant)
    bf16x8 kf[4][2];
    #pragma unroll
    for (int t = 0; t < 4; t++)
        #pragma unroll
        for (int ks = 0; ks < 2; ks++)
            kf[t][ks] = *(const bf16x8*)&kt[(t * 16 + mlane) * 72 + ks * 32 + quad * 8];

    f32x4 acc[4] = {};   // acc[ktile][reg] : key = ktile*16 + quad*4 + reg
    u16* qw = &qt[wave][0];

    const int prr = lane >> 3, pd8 = (lane & 7) * 8;   // per-lane staging coords
    u16x8 pq[8];
    #pragma unroll
    for (int t = 0; t < 8; t++)
        pq[t] = *(const u16x8*)&qbase[(size_t)(wave * 64 + t * 8 + prr) * RS_ + pd8];

    for (int i0 = wave * 64; i0 < N_; i0 += 256) {
        #pragma unroll
        for (int t = 0; t < 8; t++)
            *(u16x8*)&qw[(t * 8 + prr) * 72 + pd8] = pq[t];
        int in = i0 + 256;
        if (in < N_) {
            #pragma unroll
            for (int t = 0; t < 8; t++)
                pq[t] = *(const u16x8*)&qbase[(size_t)(in + t * 8 + prr) * RS_ + pd8];
        }
        #pragma unroll
        for (int q4 = 0; q4 < 4; q4++) {
            bf16x8 bq0 = *(const bf16x8*)&qw[(q4 * 16 + mlane) * 72 + quad * 8];
            bf16x8 bq1 = *(const bf16x8*)&qw[(q4 * 16 + mlane) * 72 + 32 + quad * 8];
            #pragma unroll
            for (int t = 0; t < 4; t++) {
                f32x4 z = {0.f, 0.f, 0.f, 0.f};
                z = __builtin_amdgcn_mfma_f32_16x16x32_bf16(kf[t][0], bq0, z, 0, 0, 0);
                z = __builtin_amdgcn_mfma_f32_16x16x32_bf16(kf[t][1], bq1, z, 0, 0, 0);
                #pragma unroll
                for (int reg = 0; reg < 4; reg++)
                    acc[t][reg] += __builtin_amdgcn_exp2f(z[reg]);
            }
        }
    }

    #pragma unroll
    for (int t = 0; t < 4; t++)
        #pragma unroll
        for (int reg = 0; reg < 4; reg++) {
            float v = acc[t][reg];
            v += __shfl_xor(v, 1, 64);
            v += __shfl_xor(v, 2, 64);
            v += __shfl_xor(v, 4, 64);
            v += __shfl_xor(v, 8, 64);
            if (mlane == 0) red[wave][t * 16 + quad * 4 + reg] = v;
        }
    __syncthreads();
    if (tid < 64) {
        float l = red[0][tid] + red[1][tid] + red[2][tid] + red[3][tid];
        li[tid] = 1.0f / l;
    }

    // --- phase 2: V tile scale + transpose (reuse kt buffer) ---
    for (int idx = tid; idx < 512; idx += 256) {
        int r = idx >> 3, d8 = (idx & 7) * 8;
        *(u16x8*)&kt[r * 72 + d8] = *(const u16x8*)&vbase[(size_t)(j0 + r) * RS_ + d8];
    }
    __syncthreads();   // covers li writes and V staging
    {
        int d = tid >> 2, j16 = (tid & 3) * 16;
        u16x8 p0, p1;
        #pragma unroll
        for (int u = 0; u < 8; u++) {
            p0[u] = f2b(b2f(kt[(j16 + u) * 72 + d]) * li[j16 + u]);
            p1[u] = f2b(b2f(kt[(j16 + 8 + u) * 72 + d]) * li[j16 + 8 + u]);
        }
        size_t o = ((size_t)bh * DH_ + d) * N_ + j0 + j16;
        *(u16x8*)&vT[o] = p0;
        *(u16x8*)&vT[o + 8] = p1;
    }
}

// ---------------------------------------------------------------------------
// Apply (32x32 MFMA): S^T = K.Qs^T -> P = exp2(S^T) (registers, lane^32
// pair-swap converts C-layout to A-layout, no LDS round-trip) -> Y += P.V'.
// R6 shape (measured best, 95us): 256 queries/block, 4 waves, 2D grid, no
// swizzle. Single LDS buffer: Q staged over the K/V region, consumed before
// the loop. Register-prefetch pipeline on K/V tiles.
// ---------------------------------------------------------------------------
__global__ __launch_bounds__(256) void attn_apply(const u16* __restrict__ qkvb,
                                                  const u16* __restrict__ vT,
                                                  u16* __restrict__ yb) {
    __shared__ u16 S[256 * 72];   // Q (256x64) at start; then K rows 0..63, vT rows 64..127

    const int tid = threadIdx.x;
    const int lane = tid & 63, wave = tid >> 6;
    const int m31 = lane & 31, half = lane >> 5;
    const int bh = blockIdx.y, b = bh >> 4, h = bh & 15;
    const int i0 = blockIdx.x * 256;

    const u16* qbase = qkvb + (size_t)b * N_ * RS_ + h * DH_;
    const u16* kbase = qbase + HID_;
    const u16* vbase = vT + (size_t)bh * DH_ * N_;

    // stage Q: 256 rows x 64 dims = 2048 chunks (Q pre-scaled by C2 upstream)
    for (int idx = tid; idx < 2048; idx += 256) {
        int r = idx >> 3, d8 = (idx & 7) * 8;
        *(u16x8*)&S[r * 72 + d8] = *(const u16x8*)&qbase[(size_t)(i0 + r) * RS_ + d8];
    }
    __syncthreads();

    // hoist Q B-frags: qf[qc][kstep], query = wave*64 + qc*32 + m31
    bf16x8 qf[2][4];
    #pragma unroll
    for (int qc = 0; qc < 2; qc++)
        #pragma unroll
        for (int ks = 0; ks < 4; ks++)
            qf[qc][ks] = *(const bf16x8*)&S[(wave * 64 + qc * 32 + m31) * 72 + ks * 16 + half * 8];

    // prefetch pipeline registers: 2 K-chunks + 2 V-chunks per thread
    const int pr = tid >> 3, pc8 = (tid & 7) * 8;   // pr 0..31
    u16x8 pk0, pk1, pv0, pv1;
    pk0 = *(const u16x8*)&kbase[(size_t)pr * RS_ + pc8];
    pk1 = *(const u16x8*)&kbase[(size_t)(pr + 32) * RS_ + pc8];
    pv0 = *(const u16x8*)&vbase[(size_t)pr * N_ + pc8];
    pv1 = *(const u16x8*)&vbase[(size_t)(pr + 32) * N_ + pc8];

    f32x16 yacc[2][2] = {};   // [qc][dtile]

    for (int j0 = 0; j0 < N_; j0 += 64) {
        __syncthreads();   // prev iteration's LDS readers done (also covers qf hoist)
        *(u16x8*)&S[pr * 72 + pc8]        = pk0;   // K rows 0..63
        *(u16x8*)&S[(pr + 32) * 72 + pc8] = pk1;
        *(u16x8*)&S[(pr + 64) * 72 + pc8] = pv0;   // vT rows 0..63 at offset 64
        *(u16x8*)&S[(pr + 96) * 72 + pc8] = pv1;
        __syncthreads();

        int jn = j0 + 64;
        if (jn < N_) {   // issue next tile's loads; consumed after next barrier
            pk0 = *(const u16x8*)&kbase[(size_t)(jn + pr) * RS_ + pc8];
            pk1 = *(const u16x8*)&kbase[(size_t)(jn + pr + 32) * RS_ + pc8];
            pv0 = *(const u16x8*)&vbase[(size_t)pr * N_ + jn + pc8];
            pv1 = *(const u16x8*)&vbase[(size_t)(pr + 32) * N_ + jn + pc8];
        }

        // --- S^T + P, per 32-key tile kt ---
        bf16x8 pa[2][4];   // PV A-frags [qc][ks16]
        #pragma unroll
        for (int kt = 0; kt < 2; kt++) {
            bf16x8 ka[4];
            #pragma unroll
            for (int ks = 0; ks < 4; ks++)
                ka[ks] = *(const bf16x8*)&S[(kt * 32 + m31) * 72 + ks * 16 + half * 8];

            f32x16 sc[2] = {};
            #pragma unroll
            for (int ks = 0; ks < 4; ks++)
                #pragma unroll
                for (int qc = 0; qc < 2; qc++)
                    sc[qc] = __builtin_amdgcn_mfma_f32_32x32x16_bf16(ka[ks], qf[qc][ks], sc[qc], 0, 0, 0);

            // exp2 -> pack (keys 8rb + 4*half + 2pp + {0,1}) -> lane^32 swap to A-layout
            #pragma unroll
            for (int qc = 0; qc < 2; qc++) {
                u32 U[4][2];
                #pragma unroll
                for (int rb = 0; rb < 4; rb++)
                    #pragma unroll
                    for (int pp = 0; pp < 2; pp++) {
                        float e0 = __builtin_amdgcn_exp2f(sc[qc][4 * rb + 2 * pp]);
                        float e1 = __builtin_amdgcn_exp2f(sc[qc][4 * rb + 2 * pp + 1]);
                        U[rb][pp] = pack2bf(e0, e1);
                    }
                #pragma unroll
                for (int ksl = 0; ksl < 2; ksl++) {
                    const int rb0 = 2 * ksl;
                    u32 a0 = U[rb0][0], a1 = U[rb0][1];
                    u32 b0 = U[rb0 + 1][0], b1 = U[rb0 + 1][1];
                    u32 e0 = half ? a0 : b0, e1 = half ? a1 : b1;   // expose partner's need
                    u32 g0 = (u32)__shfl_xor((int)e0, 32, 64);
                    u32 g1 = (u32)__shfl_xor((int)e1, 32, 64);
                    u32 o0 = half ? b0 : a0, o1 = half ? b1 : a1;   // own contribution
                    union { u32 u[4]; bf16x8 v; } cv;
                    cv.u[0] = half ? g0 : o0;
                    cv.u[1] = half ? g1 : o1;
                    cv.u[2] = half ? o0 : g0;
                    cv.u[3] = half ? o1 : g1;
                    pa[qc][2 * kt + ksl] = cv.v;
                }
            }
        }

        // --- Y += P @ V' (V pre-scaled by invl) ---
        #pragma unroll
        for (int ks16 = 0; ks16 < 4; ks16++) {
            bf16x8 vb0 = *(const bf16x8*)&S[(64 + m31) * 72 + ks16 * 16 + half * 8];
            bf16x8 vb1 = *(const bf16x8*)&S[(96 + m31) * 72 + ks16 * 16 + half * 8];
            #pragma unroll
            for (int qc = 0; qc < 2; qc++) {
                yacc[qc][0] = __builtin_amdgcn_mfma_f32_32x32x16_bf16(pa[qc][ks16], vb0, yacc[qc][0], 0, 0, 0);
                yacc[qc][1] = __builtin_amdgcn_mfma_f32_32x32x16_bf16(pa[qc][ks16], vb1, yacc[qc][1], 0, 0, 0);
            }
        }
    }

    // epilogue: query = i0 + wave*64 + qc*32 + (reg&3)+8*(reg>>2)+4*half, d = dt*32+m31
    #pragma unroll
    for (int qc = 0; qc < 2; qc++)
        #pragma unroll
        for (int dt = 0; dt < 2; dt++)
            #pragma unroll
            for (int reg = 0; reg < 16; reg++) {
                int q = i0 + wave * 64 + qc * 32 + (reg & 3) + 8 * (reg >> 2) + 4 * half;
                yb[((size_t)b * N_ + q) * HID_ + h * DH_ + dt * 32 + m31] = f2b(yacc[qc][dt][reg]);
            }
}

// ---------------------------------------------------------------------------
extern "C" void kernel_launch(void* const* d_in, const int* in_sizes, int n_in,
                              void* d_out, int out_size, void* d_ws, size_t ws_size,
                              hipStream_t stream) {
    (void)in_sizes; (void)n_in; (void)out_size; (void)ws_size;

    const float* x     = (const float*)d_in[0];
    const float* w_qkv = (const float*)d_in[1];
    const float* w_out = (const float*)d_in[2];
    const float* b_out = (const float*)d_in[3];

    u16* xb    = (u16*)d_ws;                          // [8192][1024]
    u16* wqkvT = xb    + (size_t)8192 * 1024;         // [3072][1024]
    u16* woutT = wqkvT + (size_t)3072 * 1024;         // [1024][1024]
    u16* qkvb  = woutT + (size_t)1024 * 1024;         // [8192][3072]
    u16* vTb   = qkvb  + (size_t)8192 * 3072;         // [64][64][2048]
    u16* yb    = vTb   + (size_t)64 * 64 * 2048;      // [8192][1024]

    cast_bf16<<<4096, 256, 0, stream>>>(x, xb, 8192 * 1024);
    transpose_cast<<<dim3(3072 / 64, 1024 / 64), 256, 0, stream>>>(w_qkv, wqkvT, 1024, 3072, HID_);
    transpose_cast<<<dim3(1024 / 64, 1024 / 64), 256, 0, stream>>>(w_out, woutT, 1024, 1024, 0);

    // grid = 64 m-tiles * 24 n-tiles, XCD-swizzled inside the kernel
    gemm_bt<1><<<64 * 24, 256, 0, stream>>>(
        xb, wqkvT, nullptr, qkvb, 8192, 3072, 1024);

    // fused stats + V-transpose: grid = 32 j-tiles * 64 heads, XCD-swizzled
    attn_stats_vt<<<32 * 64, 256, 0, stream>>>(qkvb, vTb);

    // R6 shape: 256 q/block, 2D grid, no swizzle
    attn_apply<<<dim3(N_ / 256, 64), 256, 0, stream>>>(qkvb, vTb, yb);

    // grid = 64 m-tiles * 8 n-tiles, XCD-swizzled
    gemm_bt<0><<<64 * 8, 256, 0, stream>>>(
        yb, woutT, b_out, d_out, 8192, 1024, 1024);
}